// Round 1
// baseline (2370.716 us; speedup 1.0000x reference)
//
#include <hip/hip_runtime.h>
#include <math.h>

#define T_SEQ 2048
#define C_DIM 1024
#define H_NUM 16
#define D_DIM 64

// ---------------------------------------------------------------------------
// fp32 GEMM: C[M,N] = A[M,K] @ B[K,N], all row-major. BM=BN=128, BK=16,
// 256 threads, 8x8 micro-tile per thread. M,N multiples of 128; K mult of 16.
// ---------------------------------------------------------------------------
__global__ __launch_bounds__(256)
void ra_gemm_f32(const float* __restrict__ A, const float* __restrict__ B,
                 float* __restrict__ C, int M, int N, int K) {
    __shared__ float As[16][128];   // As[k][m] (transposed stage)
    __shared__ float Bs[16][128];   // Bs[k][n]

    const int tid = threadIdx.x;
    const int tm  = tid >> 4;       // 0..15 -> rows tm*4, tm*4+64
    const int tn  = tid & 15;       // 0..15 -> cols tn*4, tn*4+64
    const int row0 = blockIdx.y * 128;
    const int col0 = blockIdx.x * 128;

    float acc[8][8];
#pragma unroll
    for (int i = 0; i < 8; ++i)
#pragma unroll
        for (int j = 0; j < 8; ++j) acc[i][j] = 0.f;

    for (int k0 = 0; k0 < K; k0 += 16) {
        __syncthreads();
        // A tile: rows row0..row0+127, cols k0..k0+15 -> As[k][m]
#pragma unroll
        for (int i = 0; i < 2; ++i) {
            int s  = tid * 2 + i;          // 0..511
            int m  = s >> 2;
            int kq = s & 3;
            float4 a = *reinterpret_cast<const float4*>(
                &A[(size_t)(row0 + m) * K + k0 + kq * 4]);
            As[kq * 4 + 0][m] = a.x;
            As[kq * 4 + 1][m] = a.y;
            As[kq * 4 + 2][m] = a.z;
            As[kq * 4 + 3][m] = a.w;
        }
        // B tile: rows k0..k0+15, cols col0..col0+127
#pragma unroll
        for (int i = 0; i < 2; ++i) {
            int s  = tid * 2 + i;
            int k  = s >> 5;
            int nq = s & 31;
            *reinterpret_cast<float4*>(&Bs[k][nq * 4]) =
                *reinterpret_cast<const float4*>(
                    &B[(size_t)(k0 + k) * N + col0 + nq * 4]);
        }
        __syncthreads();
#pragma unroll
        for (int k = 0; k < 16; ++k) {
            float4 a0 = *reinterpret_cast<float4*>(&As[k][tm * 4]);
            float4 a1 = *reinterpret_cast<float4*>(&As[k][tm * 4 + 64]);
            float4 b0 = *reinterpret_cast<float4*>(&Bs[k][tn * 4]);
            float4 b1 = *reinterpret_cast<float4*>(&Bs[k][tn * 4 + 64]);
            float av[8] = {a0.x, a0.y, a0.z, a0.w, a1.x, a1.y, a1.z, a1.w};
            float bv[8] = {b0.x, b0.y, b0.z, b0.w, b1.x, b1.y, b1.z, b1.w};
#pragma unroll
            for (int i = 0; i < 8; ++i)
#pragma unroll
                for (int j = 0; j < 8; ++j)
                    acc[i][j] = fmaf(av[i], bv[j], acc[i][j]);
        }
    }
#pragma unroll
    for (int i = 0; i < 8; ++i) {
        int r = row0 + ((i < 4) ? (tm * 4 + i) : (64 + tm * 4 + (i - 4)));
#pragma unroll
        for (int jh = 0; jh < 2; ++jh) {
            int c = col0 + tn * 4 + jh * 64;
            float4 v;
            v.x = acc[i][jh * 4 + 0];
            v.y = acc[i][jh * 4 + 1];
            v.z = acc[i][jh * 4 + 2];
            v.w = acc[i][jh * 4 + 3];
            *reinterpret_cast<float4*>(&C[(size_t)r * N + c]) = v;
        }
    }
}

// ---------------------------------------------------------------------------
// RoPE in-place on qkv (B,T,3C). One thread per rotation pair (b,t,mtx,h,j).
// idx = ((bt*2 + mtx)*16 + h)*32 + j
// ---------------------------------------------------------------------------
__global__ __launch_bounds__(256)
void ra_rope(float* __restrict__ qkv, int total) {
    int idx = blockIdx.x * 256 + threadIdx.x;
    if (idx >= total) return;
    int j   = idx & 31;
    int h   = (idx >> 5) & 15;
    int mtx = (idx >> 9) & 1;
    int bt  = idx >> 10;
    int t   = bt & (T_SEQ - 1);

    // inv_freq[j] = 10000^(-j/32) = 2^(-j * log2(10000)/32)
    float inv = exp2f(-(float)j * 0.41524101186092029f);
    float ang = (float)t * inv;
    float s, c;
    sincosf(ang, &s, &c);

    size_t base = (size_t)bt * 3072 + (size_t)mtx * 1024 + h * 64 + j;
    float q0 = qkv[base];
    float q1 = qkv[base + 32];
    qkv[base]      = q0 * c - q1 * s;
    qkv[base + 32] = q1 * c + q0 * s;
}

// XOR quad-swizzle for 64x64 fp32 LDS tiles read in column-slices:
// element offset of float4-quad q of row r.
__device__ __forceinline__ int ra_swz(int r, int q) {
    return r * 64 + (((q ^ ((r >> 2) & 7))) << 2);
}

// ---------------------------------------------------------------------------
// Flash attention fp32. Block = 256 threads = (tx 0..15) x (ty 0..15).
// Block handles one (b, h, 64-row Q tile); loops over 64-row K/V tiles.
// Q/K/V read from qkv buffer (stride 3072 rows); Y written (B,T,C).
// ---------------------------------------------------------------------------
__global__ __launch_bounds__(256)
void ra_attn(const float* __restrict__ qkv, float* __restrict__ Y) {
    __shared__ float Qs[64 * 64];   // swizzled, pre-scaled by 1/8
    __shared__ float Ks[64 * 64];   // swizzled
    __shared__ float Vs[64 * 64];   // linear [k][d]
    __shared__ float Ps[64 * 64];   // swizzled

    const int tid = threadIdx.x;
    const int tx  = tid & 15;       // S cols / d-quads
    const int ty  = tid >> 4;       // S row group: rows ty*4 .. ty*4+3
    const int qt  = blockIdx.x;
    const int h   = blockIdx.y;
    const int b   = blockIdx.z;
    const int t0  = qt * 64;

    const size_t base = (size_t)b * T_SEQ * 3072;
    const float* Qg = qkv + base + h * 64;
    const float* Kg = qkv + base + 1024 + h * 64;
    const float* Vg = qkv + base + 2048 + h * 64;

    // stage Q tile (scaled by 1/sqrt(D) = 0.125, exact power of two)
#pragma unroll
    for (int i = 0; i < 4; ++i) {
        int s  = tid + 256 * i;     // 0..1023
        int r  = s >> 4;
        int dq = s & 15;
        float4 q = *reinterpret_cast<const float4*>(
            &Qg[(size_t)(t0 + r) * 3072 + dq * 4]);
        q.x *= 0.125f; q.y *= 0.125f; q.z *= 0.125f; q.w *= 0.125f;
        *reinterpret_cast<float4*>(&Qs[ra_swz(r, dq)]) = q;
    }

    float m_run[4], l_run[4];
    float4 o[4];
#pragma unroll
    for (int i = 0; i < 4; ++i) {
        m_run[i] = -1e30f;
        l_run[i] = 0.f;
        o[i] = make_float4(0.f, 0.f, 0.f, 0.f);
    }

    for (int kt = 0; kt < T_SEQ / 64; ++kt) {
        __syncthreads();   // LDS reuse guard (also orders initial Q stores)
        // stage K and V tiles
#pragma unroll
        for (int i = 0; i < 4; ++i) {
            int s  = tid + 256 * i;
            int r  = s >> 4;
            int dq = s & 15;
            size_t goff = (size_t)(kt * 64 + r) * 3072 + dq * 4;
            float4 kv = *reinterpret_cast<const float4*>(&Kg[goff]);
            *reinterpret_cast<float4*>(&Ks[ra_swz(r, dq)]) = kv;
            float4 vv = *reinterpret_cast<const float4*>(&Vg[goff]);
            *reinterpret_cast<float4*>(&Vs[r * 64 + dq * 4]) = vv;
        }
        __syncthreads();

        // S = Q K^T for 4x4 micro-tile
        float sc[4][4];
#pragma unroll
        for (int i = 0; i < 4; ++i)
#pragma unroll
            for (int j = 0; j < 4; ++j) sc[i][j] = 0.f;

#pragma unroll
        for (int dq = 0; dq < 16; ++dq) {
            float4 qv[4], kv[4];
#pragma unroll
            for (int i = 0; i < 4; ++i)
                qv[i] = *reinterpret_cast<float4*>(&Qs[ra_swz(ty * 4 + i, dq)]);
#pragma unroll
            for (int j = 0; j < 4; ++j)
                kv[j] = *reinterpret_cast<float4*>(&Ks[ra_swz(tx * 4 + j, dq)]);
#pragma unroll
            for (int i = 0; i < 4; ++i)
#pragma unroll
                for (int j = 0; j < 4; ++j) {
                    sc[i][j] = fmaf(qv[i].x, kv[j].x, sc[i][j]);
                    sc[i][j] = fmaf(qv[i].y, kv[j].y, sc[i][j]);
                    sc[i][j] = fmaf(qv[i].z, kv[j].z, sc[i][j]);
                    sc[i][j] = fmaf(qv[i].w, kv[j].w, sc[i][j]);
                }
        }

        // online softmax update (row reduction across the 16 tx lanes)
#pragma unroll
        for (int i = 0; i < 4; ++i) {
            float mloc = fmaxf(fmaxf(sc[i][0], sc[i][1]),
                               fmaxf(sc[i][2], sc[i][3]));
            mloc = fmaxf(mloc, __shfl_xor(mloc, 1));
            mloc = fmaxf(mloc, __shfl_xor(mloc, 2));
            mloc = fmaxf(mloc, __shfl_xor(mloc, 4));
            mloc = fmaxf(mloc, __shfl_xor(mloc, 8));
            float mnew  = fmaxf(m_run[i], mloc);
            float alpha = __expf(m_run[i] - mnew);
            float p0 = __expf(sc[i][0] - mnew);
            float p1 = __expf(sc[i][1] - mnew);
            float p2 = __expf(sc[i][2] - mnew);
            float p3 = __expf(sc[i][3] - mnew);
            float rs = p0 + p1 + p2 + p3;
            rs += __shfl_xor(rs, 1);
            rs += __shfl_xor(rs, 2);
            rs += __shfl_xor(rs, 4);
            rs += __shfl_xor(rs, 8);
            l_run[i] = l_run[i] * alpha + rs;
            m_run[i] = mnew;
            o[i].x *= alpha; o[i].y *= alpha; o[i].z *= alpha; o[i].w *= alpha;
            *reinterpret_cast<float4*>(&Ps[ra_swz(ty * 4 + i, tx)]) =
                make_float4(p0, p1, p2, p3);
        }
        __syncthreads();

        // O += P @ V  (thread: 4 rows x d-quad tx)
#pragma unroll
        for (int kq = 0; kq < 16; ++kq) {
            float4 pv[4];
#pragma unroll
            for (int i = 0; i < 4; ++i)
                pv[i] = *reinterpret_cast<float4*>(&Ps[ra_swz(ty * 4 + i, kq)]);
            float4 v0 = *reinterpret_cast<float4*>(&Vs[(kq * 4 + 0) * 64 + tx * 4]);
            float4 v1 = *reinterpret_cast<float4*>(&Vs[(kq * 4 + 1) * 64 + tx * 4]);
            float4 v2 = *reinterpret_cast<float4*>(&Vs[(kq * 4 + 2) * 64 + tx * 4]);
            float4 v3 = *reinterpret_cast<float4*>(&Vs[(kq * 4 + 3) * 64 + tx * 4]);
#pragma unroll
            for (int i = 0; i < 4; ++i) {
                o[i].x = fmaf(pv[i].x, v0.x, fmaf(pv[i].y, v1.x,
                         fmaf(pv[i].z, v2.x, fmaf(pv[i].w, v3.x, o[i].x))));
                o[i].y = fmaf(pv[i].x, v0.y, fmaf(pv[i].y, v1.y,
                         fmaf(pv[i].z, v2.y, fmaf(pv[i].w, v3.y, o[i].y))));
                o[i].z = fmaf(pv[i].x, v0.z, fmaf(pv[i].y, v1.z,
                         fmaf(pv[i].z, v2.z, fmaf(pv[i].w, v3.z, o[i].z))));
                o[i].w = fmaf(pv[i].x, v0.w, fmaf(pv[i].y, v1.w,
                         fmaf(pv[i].z, v2.w, fmaf(pv[i].w, v3.w, o[i].w))));
            }
        }
    }

    // epilogue: normalize and write Y (B,T,C)
#pragma unroll
    for (int i = 0; i < 4; ++i) {
        float inv = 1.0f / l_run[i];
        float4 r;
        r.x = o[i].x * inv; r.y = o[i].y * inv;
        r.z = o[i].z * inv; r.w = o[i].w * inv;
        *reinterpret_cast<float4*>(
            &Y[((size_t)b * T_SEQ + t0 + ty * 4 + i) * C_DIM + h * 64 + tx * 4]) = r;
    }
}

// ---------------------------------------------------------------------------
extern "C" void kernel_launch(void* const* d_in, const int* in_sizes, int n_in,
                              void* d_out, int out_size, void* d_ws, size_t ws_size,
                              hipStream_t stream) {
    const float* x      = (const float*)d_in[0];
    const float* W_attn = (const float*)d_in[1];
    const float* W_proj = (const float*)d_in[2];
    float* out = (float*)d_out;

    const int B = in_sizes[0] / (T_SEQ * C_DIM);   // 4
    const int M = B * T_SEQ;                        // 8192

    float* qkv = (float*)d_ws;                      // M x 3072  (96 MB)
    float* Y   = qkv + (size_t)M * 3 * C_DIM;       // M x 1024  (32 MB)

    // 1) qkv = x @ W_attn
    dim3 g1(3 * C_DIM / 128, M / 128);
    hipLaunchKernelGGL(ra_gemm_f32, g1, dim3(256), 0, stream,
                       x, W_attn, qkv, M, 3 * C_DIM, C_DIM);

    // 2) RoPE in place on q,k
    int total = M * 2 * H_NUM * 32;                 // 8.4M pairs
    hipLaunchKernelGGL(ra_rope, dim3(total / 256), dim3(256), 0, stream,
                       qkv, total);

    // 3) flash attention -> Y (B,T,C)
    hipLaunchKernelGGL(ra_attn, dim3(T_SEQ / 64, H_NUM, B), dim3(256), 0, stream,
                       qkv, Y);

    // 4) out = Y @ W_proj
    dim3 g2(C_DIM / 128, M / 128);
    hipLaunchKernelGGL(ra_gemm_f32, g2, dim3(256), 0, stream,
                       Y, W_proj, out, M, C_DIM, C_DIM);
}

// Round 10
// 380.211 us; speedup vs baseline: 6.2353x; 6.2353x over previous
//
#include <hip/hip_runtime.h>
#include <math.h>

#define T_SEQ 2048
#define C_DIM 1024
#define H_NUM 16
#define D_DIM 64

typedef _Float16 f16x8 __attribute__((ext_vector_type(8)));
typedef _Float16 f16x4 __attribute__((ext_vector_type(4)));
typedef float    f32x4_t __attribute__((ext_vector_type(4)));

// ---------------------------------------------------------------------------
// x (fp32) -> xh (fp16), element-count/4 float4 units
// ---------------------------------------------------------------------------
__global__ __launch_bounds__(256)
void ra_conv_f16(const float* __restrict__ src, _Float16* __restrict__ dst,
                 int n4) {
    int i = blockIdx.x * 256 + threadIdx.x;
    if (i >= n4) return;
    float4 v = reinterpret_cast<const float4*>(src)[i];
    f16x4 h = { (_Float16)v.x, (_Float16)v.y, (_Float16)v.z, (_Float16)v.w };
    reinterpret_cast<f16x4*>(dst)[i] = h;
}

// ---------------------------------------------------------------------------
// W[R][C] fp32 -> Wt[C][R] fp16 (transpose+convert), 64x64 LDS tiles.
// R, C multiples of 64.
// ---------------------------------------------------------------------------
__global__ __launch_bounds__(256)
void ra_transpose_conv(const float* __restrict__ W, _Float16* __restrict__ Wt,
                       int R, int C) {
    __shared__ _Float16 tile[64][68];   // +4 pad keeps f16x4 rows 8B-aligned
    const int tid = threadIdx.x;
    const int r0 = blockIdx.y * 64, c0 = blockIdx.x * 64;
#pragma unroll
    for (int i = 0; i < 4; ++i) {
        int s = tid + 256 * i;          // 64 rows x 16 float4 quads
        int r = s >> 4, cq = s & 15;
        float4 w = *reinterpret_cast<const float4*>(
            &W[(size_t)(r0 + r) * C + c0 + cq * 4]);
        f16x4 h = { (_Float16)w.x, (_Float16)w.y, (_Float16)w.z, (_Float16)w.w };
        *reinterpret_cast<f16x4*>(&tile[r][cq * 4]) = h;
    }
    __syncthreads();
#pragma unroll
    for (int i = 0; i < 4; ++i) {
        int s = tid + 256 * i;          // 64 cols x 16 row-quads
        int c = s >> 4, rq = s & 15;
        f16x4 o = { tile[rq * 4 + 0][c], tile[rq * 4 + 1][c],
                    tile[rq * 4 + 2][c], tile[rq * 4 + 3][c] };
        *reinterpret_cast<f16x4*>(&Wt[(size_t)(c0 + c) * R + r0 + rq * 4]) = o;
    }
}

// ---------------------------------------------------------------------------
// fp16 MFMA GEMM: C[M,N] = A[M,K] @ Bt[N,K]^T. A,Bt fp16 row-major (Bt is
// the N-major transposed weight), C fp32 or fp16. BM=BN=128, BK=32,
// 256 thr = 4 waves (2x2), each wave 64x64 via 4x4 MFMAs of 16x16x32.
// K multiple of 32. LDS tiles [128][32] f16 linear: frag/stage access is
// 16 rows x 4 octets -> bank-quad (4r+g)%8, 8 lanes/quad = b128 floor.
// ---------------------------------------------------------------------------
template <bool F16OUT>
__global__ __launch_bounds__(256)
void ra_gemm_f16(const _Float16* __restrict__ A, const _Float16* __restrict__ Bt,
                 void* __restrict__ Cout, int M, int N, int K) {
    __shared__ _Float16 AhS[128 * 32];
    __shared__ _Float16 BhS[128 * 32];

    const int tid  = threadIdx.x;
    const int lane = tid & 63;
    const int wave = tid >> 6;
    const int wm   = wave >> 1, wn = wave & 1;
    const int lq   = lane & 15;      // fragment row/col
    const int lg   = lane >> 4;      // k-octet group
    const int row0 = blockIdx.y * 128;
    const int col0 = blockIdx.x * 128;

    f32x4_t acc[4][4];
#pragma unroll
    for (int i = 0; i < 4; ++i)
#pragma unroll
        for (int j = 0; j < 4; ++j) acc[i][j] = {0.f, 0.f, 0.f, 0.f};

    for (int k0 = 0; k0 < K; k0 += 32) {
        __syncthreads();
        // stage A,B tiles: 512 f16x8 units each, 2 per thread, coalesced 16B
#pragma unroll
        for (int i = 0; i < 2; ++i) {
            int s = tid + 256 * i;
            int r = s >> 2, g = s & 3;
            *reinterpret_cast<f16x8*>(&AhS[r * 32 + g * 8]) =
                *reinterpret_cast<const f16x8*>(
                    &A[(size_t)(row0 + r) * K + k0 + g * 8]);
            *reinterpret_cast<f16x8*>(&BhS[r * 32 + g * 8]) =
                *reinterpret_cast<const f16x8*>(
                    &Bt[(size_t)(col0 + r) * K + k0 + g * 8]);
        }
        __syncthreads();

        f16x8 af[4], bf[4];
#pragma unroll
        for (int t = 0; t < 4; ++t) {
            af[t] = *reinterpret_cast<const f16x8*>(
                &AhS[(wm * 64 + t * 16 + lq) * 32 + lg * 8]);
            bf[t] = *reinterpret_cast<const f16x8*>(
                &BhS[(wn * 64 + t * 16 + lq) * 32 + lg * 8]);
        }
#pragma unroll
        for (int mt = 0; mt < 4; ++mt)
#pragma unroll
            for (int nt = 0; nt < 4; ++nt)
                acc[mt][nt] = __builtin_amdgcn_mfma_f32_16x16x32_f16(
                    af[mt], bf[nt], acc[mt][nt], 0, 0, 0);
    }

    // epilogue: D lane layout col=lane&15, row=4*(lane>>4)+r (m89-verified)
#pragma unroll
    for (int mt = 0; mt < 4; ++mt)
#pragma unroll
        for (int nt = 0; nt < 4; ++nt) {
            int c = col0 + wn * 64 + nt * 16 + lq;
#pragma unroll
            for (int r = 0; r < 4; ++r) {
                int rr = row0 + wm * 64 + mt * 16 + 4 * lg + r;
                if (F16OUT)
                    ((_Float16*)Cout)[(size_t)rr * N + c] =
                        (_Float16)acc[mt][nt][r];
                else
                    ((float*)Cout)[(size_t)rr * N + c] = acc[mt][nt][r];
            }
        }
}

// ---------------------------------------------------------------------------
// RoPE in-place on fp16 qkv (B,T,3C); folds the 1/8 softmax scale into q.
// One thread per rotation pair. (math validated in round 1 at absmax 9.8e-4)
// ---------------------------------------------------------------------------
__global__ __launch_bounds__(256)
void ra_rope_f16(_Float16* __restrict__ qkv, int total) {
    int idx = blockIdx.x * 256 + threadIdx.x;
    if (idx >= total) return;
    int j   = idx & 31;
    int h   = (idx >> 5) & 15;
    int mtx = (idx >> 9) & 1;
    int bt  = idx >> 10;
    int t   = bt & (T_SEQ - 1);

    float inv = exp2f(-(float)j * 0.41524101186092029f);
    float ang = (float)t * inv;
    float s, c;
    sincosf(ang, &s, &c);
    float scale = (mtx == 0) ? 0.125f : 1.0f;   // q pre-scaled by 1/sqrt(D)

    size_t base = (size_t)bt * 3072 + (size_t)mtx * 1024 + h * 64 + j;
    float q0 = (float)qkv[base];
    float q1 = (float)qkv[base + 32];
    qkv[base]      = (_Float16)((q0 * c - q1 * s) * scale);
    qkv[base + 32] = (_Float16)((q1 * c + q0 * s) * scale);
}

// ---------------------------------------------------------------------------
// Flash attention, fp16 MFMA (16x16x32, fp32 accum). fp16 qkv in, fp16 Y out.
// Block = 256 thr = 4 waves; block: (b,h,64 q-rows); wave: 16 q-rows.
// Swapped QK^T: St = K_tile @ Q^T -> lane holds one q-row (D-layout
// col=lane&15, m89-verified); softmax via shfl_xor(16/32).
// PV: Ot = V^T @ P^T, V staged transposed. P^T staged via per-wave LDS with
// an explicit __syncthreads() between write and read: round 1's passing
// kernel had this barrier; round 9's barrier-free variant failed POST-TIMING
// only (call-1 correct, warm replays wrong) -- restore the proven structure.
// Octet XOR swizzles keep frag reads at the b128 floor.
// ---------------------------------------------------------------------------
__global__ __launch_bounds__(256)
void ra_attn_mfma(const _Float16* __restrict__ qkv, _Float16* __restrict__ Y) {
    __shared__ __align__(16) unsigned char smem_raw[24576];
    _Float16* Ks = (_Float16*)smem_raw;            // [64 kv][64 d]   8KB
    _Float16* Vt = (_Float16*)(smem_raw + 8192);   // [64 d][64 kv]   8KB
    _Float16* Pt = (_Float16*)(smem_raw + 16384);  // [4w][16 q][64]  8KB

    const int tid  = threadIdx.x;
    const int lane = tid & 63;
    const int wave = tid >> 6;
    const int lq   = lane & 15;
    const int lg   = lane >> 4;
    const int swz  = (lq & 7) << 3;

    const int t0 = blockIdx.x * 64;
    const int h  = blockIdx.y;
    const int b  = blockIdx.z;

    const _Float16* Qg = qkv + (size_t)b * T_SEQ * 3072 + h * 64;
    const _Float16* Kg = Qg + 1024;
    const _Float16* Vg = Qg + 2048;

    // Q fragments (B operand of St): q pre-scaled by RoPE, direct f16x8 loads
    f16x8 qf[2];
    {
        const _Float16* qrow = Qg + (size_t)(t0 + wave * 16 + lq) * 3072 + lg * 8;
        qf[0] = *reinterpret_cast<const f16x8*>(qrow);
        qf[1] = *reinterpret_cast<const f16x8*>(qrow + 32);
    }

    const f32x4_t vzero = {0.f, 0.f, 0.f, 0.f};
    float m_run = -1e30f, l_run = 0.f;
    f32x4_t o[4];
#pragma unroll
    for (int i = 0; i < 4; ++i) o[i] = vzero;

    const int dsub = tid & 15, kvq = tid >> 4;

    for (int kt = 0; kt < T_SEQ / 64; ++kt) {
        __syncthreads();                       // guard Ks/Vt reuse
        const int kvb = kt * 64;
        // stage K [kv][d^((kv&7)<<3)]: f16x4 copies, 128B/16-lane coalesced
#pragma unroll
        for (int i = 0; i < 4; ++i) {
            int s  = tid + 256 * i;
            int kv = s >> 4, dq = s & 15;
            f16x4 hh = *reinterpret_cast<const f16x4*>(
                &Kg[(size_t)(kvb + kv) * 3072 + dq * 4]);
            *reinterpret_cast<f16x4*>(
                &Ks[kv * 64 + ((dq * 4) ^ ((kv & 7) << 3))]) = hh;
        }
        // stage V transposed [d][kv^((d&7)<<3)]: 2B gathers (K/V slab L2-hot)
#pragma unroll
        for (int i = 0; i < 4; ++i) {
            int d = dsub + 16 * i;
            const _Float16* vcol = &Vg[(size_t)(kvb + kvq * 4) * 3072 + d];
            f16x4 hh = { vcol[0], vcol[3072], vcol[6144], vcol[9216] };
            *reinterpret_cast<f16x4*>(
                &Vt[d * 64 + ((kvq * 4) ^ ((d & 7) << 3))]) = hh;
        }
        __syncthreads();

        // St[t] = K_tile(t) @ Q^T
        f32x4_t st[4];
#pragma unroll
        for (int t = 0; t < 4; ++t) {
            st[t] = vzero;
#pragma unroll
            for (int mk = 0; mk < 2; ++mk) {
                f16x8 ak = *reinterpret_cast<const f16x8*>(
                    &Ks[(t * 16 + lq) * 64 + ((lg * 8 + mk * 32) ^ swz)]);
                st[t] = __builtin_amdgcn_mfma_f32_16x16x32_f16(
                    ak, qf[mk], st[t], 0, 0, 0);
            }
        }

        // online softmax for q-row lq (16 keys/lane, reduce over lg groups)
        float mloc = -1e30f;
#pragma unroll
        for (int t = 0; t < 4; ++t)
#pragma unroll
            for (int r = 0; r < 4; ++r) mloc = fmaxf(mloc, st[t][r]);
        mloc = fmaxf(mloc, __shfl_xor(mloc, 16));
        mloc = fmaxf(mloc, __shfl_xor(mloc, 32));
        float mnew  = fmaxf(m_run, mloc);
        float alpha = __expf(m_run - mnew);
        float rs = 0.f;
        float p[4][4];
#pragma unroll
        for (int t = 0; t < 4; ++t)
#pragma unroll
            for (int r = 0; r < 4; ++r) {
                p[t][r] = __expf(st[t][r] - mnew);
                rs += p[t][r];
            }
        rs += __shfl_xor(rs, 16);
        rs += __shfl_xor(rs, 32);
        l_run = l_run * alpha + rs;
        m_run = mnew;
#pragma unroll
        for (int i = 0; i < 4; ++i) o[i] *= alpha;

        // P^T -> per-wave LDS [q=lq][kv ^ swz]
        _Float16* Pw = Pt + wave * 1024 + lq * 64;
#pragma unroll
        for (int t = 0; t < 4; ++t) {
            f16x4 ph = { (_Float16)p[t][0], (_Float16)p[t][1],
                         (_Float16)p[t][2], (_Float16)p[t][3] };
            *reinterpret_cast<f16x4*>(&Pw[(t * 16 + lg * 4) ^ swz]) = ph;
        }
        __syncthreads();   // P write->read sync (round-1-proven structure;
                           // barrier-free variant diverged on warm replays)

        // Ot += V^T @ P^T
        f16x8 bp[2];
#pragma unroll
        for (int mk = 0; mk < 2; ++mk)
            bp[mk] = *reinterpret_cast<const f16x8*>(
                &Pw[(lg * 8 + mk * 32) ^ swz]);
#pragma unroll
        for (int dt = 0; dt < 4; ++dt) {
#pragma unroll
            for (int mk = 0; mk < 2; ++mk) {
                f16x8 av = *reinterpret_cast<const f16x8*>(
                    &Vt[(dt * 16 + lq) * 64 + ((lg * 8 + mk * 32) ^ swz)]);
                o[dt] = __builtin_amdgcn_mfma_f32_16x16x32_f16(
                    av, bp[mk], o[dt], 0, 0, 0);
            }
        }
    }

    // epilogue: Ot -> LDS f32 (quad-swizzle) -> Y fp16
    __syncthreads();
    float* Of = (float*)smem_raw;            // [64 q][64 d] 16KB (reuse Ks+Vt)
    {
        float inv = 1.0f / l_run;
        int q = wave * 16 + lq;
#pragma unroll
        for (int dt = 0; dt < 4; ++dt)
#pragma unroll
            for (int r = 0; r < 4; ++r) {
                int d = dt * 16 + lg * 4 + r;
                Of[q * 64 + (d ^ ((q & 7) << 2))] = o[dt][r] * inv;
            }
    }
    __syncthreads();
#pragma unroll
    for (int i = 0; i < 4; ++i) {
        int s = tid + 256 * i;
        int row = s >> 4, dq = s & 15;
        float4 v = *reinterpret_cast<float4*>(
            &Of[row * 64 + ((dq * 4) ^ ((row & 7) << 2))]);
        f16x4 hv = { (_Float16)v.x, (_Float16)v.y, (_Float16)v.z, (_Float16)v.w };
        *reinterpret_cast<f16x4*>(
            &Y[((size_t)b * T_SEQ + t0 + row) * C_DIM + h * 64 + dq * 4]) = hv;
    }
}

// ---------------------------------------------------------------------------
extern "C" void kernel_launch(void* const* d_in, const int* in_sizes, int n_in,
                              void* d_out, int out_size, void* d_ws, size_t ws_size,
                              hipStream_t stream) {
    const float* x      = (const float*)d_in[0];
    const float* W_attn = (const float*)d_in[1];
    const float* W_proj = (const float*)d_in[2];
    float* out = (float*)d_out;

    const int B = in_sizes[0] / (T_SEQ * C_DIM);   // 4
    const int M = B * T_SEQ;                        // 8192

    // fp16 workspace layout (byte offsets), total 88 MB < 128 MB
    unsigned char* ws = (unsigned char*)d_ws;
    _Float16* xh   = (_Float16*)(ws);                        // 16 MB
    _Float16* qkvh = (_Float16*)(ws + (16u << 20));          // 48 MB
    _Float16* Yh   = (_Float16*)(ws + (64u << 20));          // 16 MB
    _Float16* WaT  = (_Float16*)(ws + (80u << 20));          //  6 MB
    _Float16* WpT  = (_Float16*)(ws + (86u << 20));          //  2 MB

    // 1) convert x -> fp16
    int n4 = M * C_DIM / 4;
    hipLaunchKernelGGL(ra_conv_f16, dim3((n4 + 255) / 256), dim3(256), 0,
                       stream, x, xh, n4);

    // 2) transpose+convert weights to N-major fp16
    hipLaunchKernelGGL(ra_transpose_conv, dim3(3 * C_DIM / 64, C_DIM / 64),
                       dim3(256), 0, stream, W_attn, WaT, C_DIM, 3 * C_DIM);
    hipLaunchKernelGGL(ra_transpose_conv, dim3(C_DIM / 64, C_DIM / 64),
                       dim3(256), 0, stream, W_proj, WpT, C_DIM, C_DIM);

    // 3) qkv = x @ W_attn   (fp16 out)
    hipLaunchKernelGGL((ra_gemm_f16<true>), dim3(3 * C_DIM / 128, M / 128),
                       dim3(256), 0, stream, xh, WaT, (void*)qkvh,
                       M, 3 * C_DIM, C_DIM);

    // 4) RoPE in place on q,k (q pre-scaled by 1/8)
    int total = M * 2 * H_NUM * 32;
    hipLaunchKernelGGL(ra_rope_f16, dim3(total / 256), dim3(256), 0, stream,
                       qkvh, total);

    // 5) flash attention (fp16 MFMA) -> Yh
    hipLaunchKernelGGL(ra_attn_mfma, dim3(T_SEQ / 64, H_NUM, B), dim3(256), 0,
                       stream, qkvh, Yh);

    // 6) out = Y @ W_proj   (fp32 out)
    hipLaunchKernelGGL((ra_gemm_f16<false>), dim3(C_DIM / 128, M / 128),
                       dim3(256), 0, stream, Yh, WpT, (void*)out,
                       M, C_DIM, C_DIM);
}